// Round 19
// baseline (191.926 us; speedup 1.0000x reference)
//
#include <hip/hip_runtime.h>
#include <hip/hip_bf16.h>

typedef __attribute__((ext_vector_type(8))) short short8;
typedef __attribute__((ext_vector_type(4))) float f32x4;

static __device__ __forceinline__ unsigned short f2bf(float f) {
    unsigned int u = __builtin_bit_cast(unsigned int, f);
    u += 0x7fff + ((u >> 16) & 1);   // round-to-nearest-even
    return (unsigned short)(u >> 16);
}

static __device__ __forceinline__ float bf2f(unsigned short u) {
    return __builtin_bit_cast(float, (unsigned int)u << 16);
}

// direct HBM -> LDS DMA, 16B/lane; LDS dest is wave-uniform base (HW adds lane*16)
static __device__ __forceinline__ void gl_lds16(const unsigned short* g, unsigned short* l) {
    __builtin_amdgcn_global_load_lds(
        (const __attribute__((address_space(1))) unsigned int*)g,
        (__attribute__((address_space(3))) unsigned int*)l, 16, 0, 0);
}

// ---------------- fused prep: x->bf16 convert + both weight transposes -----
// 1-D grid, block-range dispatch: [0,4096) convert x (8 f32/thread);
// [4096,4864) transpose w_qkv [1024][3072] -> wqt [3072][1024];
// [4864,5120) transpose w_proj [1024][1024] -> wpt [1024][1024].
__global__ __launch_bounds__(256) void k_prep(
    const float* __restrict__ x,      unsigned short* __restrict__ xb,
    const float* __restrict__ w_qkv,  unsigned short* __restrict__ wqt,
    const float* __restrict__ w_proj, unsigned short* __restrict__ wpt)
{
    __shared__ unsigned short tile[64][72];
    const int id = blockIdx.x;
    const int tid = threadIdx.x;

    if (id < 4096) {                      // x convert: 8.39e6 elems / 8 / 256
        long i = ((long)id * 256 + tid) * 8;
        const f32x4 a = *reinterpret_cast<const f32x4*>(x + i);
        const f32x4 b = *reinterpret_cast<const f32x4*>(x + i + 4);
        union { unsigned short u[8]; uint4 v; } o;
        o.u[0] = f2bf(a[0]); o.u[1] = f2bf(a[1]); o.u[2] = f2bf(a[2]); o.u[3] = f2bf(a[3]);
        o.u[4] = f2bf(b[0]); o.u[5] = f2bf(b[1]); o.u[6] = f2bf(b[2]); o.u[7] = f2bf(b[3]);
        *reinterpret_cast<uint4*>(xb + i) = o.v;
        return;
    }
    const float* w;
    unsigned short* wt;
    int k0, n0, N;
    if (id < 4864) {                      // w_qkv transpose (16 x 48 tiles)
        const int t = id - 4096;
        w = w_qkv; wt = wqt; N = 3072;
        k0 = (t & 15) * 64; n0 = (t >> 4) * 64;
    } else {                              // w_proj transpose (16 x 16 tiles)
        const int t = id - 4864;
        w = w_proj; wt = wpt; N = 1024;
        k0 = (t & 15) * 64; n0 = (t >> 4) * 64;
    }
    const int K = 1024;
#pragma unroll
    for (int it = 0; it < 4; ++it) {
        int idx = it * 256 + tid;          // 1024 float4 chunks
        int kl = idx >> 4;
        int nl = (idx & 15) * 4;
        f32x4 v = *reinterpret_cast<const f32x4*>(w + (long)(k0 + kl) * N + n0 + nl);
        tile[kl][nl + 0] = f2bf(v[0]);
        tile[kl][nl + 1] = f2bf(v[1]);
        tile[kl][nl + 2] = f2bf(v[2]);
        tile[kl][nl + 3] = f2bf(v[3]);
    }
    __syncthreads();
#pragma unroll
    for (int it = 0; it < 2; ++it) {
        int idx = it * 256 + tid;          // 512 chunks of 8
        int nl = idx >> 3;
        int c  = (idx & 7) * 8;
        union { unsigned short u[8]; uint4 v; } o;
#pragma unroll
        for (int j = 0; j < 8; ++j) o.u[j] = tile[c + j][nl];
        *reinterpret_cast<uint4*>(wt + (long)(n0 + nl) * K + k0 + c) = o.v;
    }
}

// ---------------- GEMM: C[M][N] = A[M][K] * Bt[N][K]^T + bias --------------
// A, Bt bf16 K-major; out bf16 (OUTF32=0) or f32 (OUTF32=1).
// 128^2 2-phase dbuf gl_lds + counted vmcnt (R13/R16-verified best).
// Fused V-transpose epilogue (R17): QKV blocks with n0 >= 2048 write the
// accumulator directly in vt[bh][d][t] layout.
// NEW (R19): bijective XCD remap (T1) — consecutive remapped ids share
// operand panels on one XCD's L2 (B-panel re-read M/128=64x, A-panel
// N/128x: ~780MB logical traffic was crossing to L3). Grids divide by 8
// exactly (1536 = 8*192, 512 = 8*64).
template <int OUTF32>
__global__ __launch_bounds__(256) void k_gemm_bt(
    const unsigned short* __restrict__ A,
    const unsigned short* __restrict__ Bt,
    const float* __restrict__ bias,
    void* __restrict__ Cv,
    unsigned short* __restrict__ vtout,   // nullptr for proj
    int M, int N, int K)
{
    __shared__ __align__(16) unsigned short As[2][128][64];
    __shared__ __align__(16) unsigned short Bs[2][128][64];
    const int tid = threadIdx.x;
    // bijective XCD remap
    const int nwg = gridDim.x * gridDim.y;
    int id = blockIdx.x + gridDim.x * blockIdx.y;
    id = (id & 7) * (nwg >> 3) + (id >> 3);
    const int m0 = (id % gridDim.x) * 128;
    const int n0 = (id / gridDim.x) * 128;
    const int w = tid >> 6, lane = tid & 63;
    const int wr = (w >> 1) * 64, wc = (w & 1) * 64;
    const int l4 = lane >> 4, l15 = lane & 15;
    // staging: per-lane pre-swizzled global source slot
    const int lrow  = lane >> 3;               // row within 8-row chunk
    const int lslot = (lane & 7) ^ lrow;       // swizzled 16B source slot

    auto stage = [&](int buf, int k0) {        // 8 gl_lds per wave
#pragma unroll
        for (int it = 0; it < 4; ++it) {
            const int rb = (w * 4 + it) * 8;   // 8-row chunk base
            gl_lds16(A  + (long)(m0 + rb + lrow) * K + k0 + lslot * 8, &As[buf][rb][0]);
            gl_lds16(Bt + (long)(n0 + rb + lrow) * K + k0 + lslot * 8, &Bs[buf][rb][0]);
        }
    };

    f32x4 acc[4][4] = {};
    const int nk = K / 64;
    stage(0, 0);
    for (int kt = 0; kt < nk; ++kt) {
        const int cur = kt & 1;
        if (kt + 1 < nk) {
            stage(cur ^ 1, (kt + 1) * 64);     // 8 loads stay in flight
            asm volatile("s_waitcnt vmcnt(8)" ::: "memory");   // stage-kt landed
        } else {
            asm volatile("s_waitcnt vmcnt(0)" ::: "memory");
        }
        __builtin_amdgcn_sched_barrier(0);
        __builtin_amdgcn_s_barrier();          // all waves' stage-kt landed
        __builtin_amdgcn_sched_barrier(0);
#pragma unroll
        for (int kk = 0; kk < 2; ++kk) {
            short8 af[4], bf[4];
#pragma unroll
            for (int m = 0; m < 4; ++m) {
                const int r = wr + m * 16 + l15;
                af[m] = *reinterpret_cast<const short8*>(&As[cur][r][((kk * 4 + l4) ^ (r & 7)) * 8]);
            }
#pragma unroll
            for (int n = 0; n < 4; ++n) {
                const int r = wc + n * 16 + l15;
                bf[n] = *reinterpret_cast<const short8*>(&Bs[cur][r][((kk * 4 + l4) ^ (r & 7)) * 8]);
            }
#pragma unroll
            for (int m = 0; m < 4; ++m)
#pragma unroll
                for (int n = 0; n < 4; ++n)
                    acc[m][n] = __builtin_amdgcn_mfma_f32_16x16x32_bf16(af[m], bf[n], acc[m][n], 0, 0, 0);
        }
        __builtin_amdgcn_sched_barrier(0);
        asm volatile("s_waitcnt lgkmcnt(0)" ::: "memory");   // my LDS reads done
        __builtin_amdgcn_s_barrier();          // everyone's reads done -> buffer reusable
        __builtin_amdgcn_sched_barrier(0);
    }
    // epilogue
    if (!OUTF32 && vtout && n0 >= 2048) {
        // V-third of QKV: write directly in vt[bh=b*16+hd][d][t] layout.
#pragma unroll
        for (int n = 0; n < 4; ++n) {
            const int col = n0 + wc + n * 16 + l15;       // 2048..3071
            const float bv = bias[col];
            const int cp = col - 2048;                    // 0..1023
            const int hd = cp >> 6, d = cp & 63;
#pragma unroll
            for (int m = 0; m < 4; ++m) {
                const int row0 = m0 + wr + m * 16 + l4 * 4;   // 4 consecutive t
                const int b = row0 >> 11;                 // /2048
                const int t = row0 & 2047;
                unsigned int u01 =
                    ((unsigned int)f2bf(acc[m][n][1] + bv) << 16) |
                    (unsigned int)f2bf(acc[m][n][0] + bv);
                unsigned int u23 =
                    ((unsigned int)f2bf(acc[m][n][3] + bv) << 16) |
                    (unsigned int)f2bf(acc[m][n][2] + bv);
                *reinterpret_cast<uint2*>(
                    vtout + ((long)(b * 16 + hd) * 64 + d) * 2048 + t) =
                    make_uint2(u01, u23);
            }
        }
        return;
    }
#pragma unroll
    for (int n = 0; n < 4; ++n) {
        const int col = n0 + wc + n * 16 + l15;
        const float bv = bias[col];
#pragma unroll
        for (int m = 0; m < 4; ++m) {
            const int row = m0 + wr + m * 16 + l4 * 4;
#pragma unroll
            for (int i = 0; i < 4; ++i) {
                float v = acc[m][n][i] + bv;
                if (OUTF32)
                    reinterpret_cast<float*>(Cv)[(long)(row + i) * N + col] = v;
                else
                    reinterpret_cast<unsigned short*>(Cv)[(long)(row + i) * N + col] = f2bf(v);
            }
        }
    }
}

// ---------------- causal flash attention v6 (R12/R16-R18 known-good) -------
// Paired q-tiles sequential, gl_lds dbuf + both-sides swizzle, XCD remap,
// fixed-max softmax, MFMA row-sums, setprio, swapped QK^T + packed P-writes.
__global__ __launch_bounds__(256, 4) void k_attn(
    const unsigned short* __restrict__ qkv,
    const unsigned short* __restrict__ vt,
    unsigned short* __restrict__ y, int T)
{
    __shared__ __align__(16) unsigned short Kb[2][64][64];
    __shared__ __align__(16) unsigned short Vb[2][64][64];
    __shared__ __align__(16) unsigned short Ps[4][16][64];   // [wave][q][k]
    const int nQT = T >> 6;

    // XCD-aware bijective remap (1024 = 8 * 128, exact)
    int n = blockIdx.x + gridDim.x * blockIdx.y;          // 0..1023
    n = (n & 7) * ((gridDim.x * gridDim.y) >> 3) + (n >> 3);
    const int qa = n & 15;                // 0..15
    const int qb = nQT - 1 - qa;          // 31..16
    const int bh = n >> 4;
    const int b = bh >> 4, h = bh & 15;
    const int tid = threadIdx.x, w = tid >> 6, lane = tid & 63;
    const int l4 = lane >> 4, l15 = lane & 15;

    const float SC = 0.125f * 1.44269504f;  // 1/sqrt(64) * log2(e)

    // Q fragments for both tiles, pre-scaled by SC
    const unsigned short* qpA = qkv + (long)(b * T + qa * 64 + w * 16 + l15) * 3072 + h * 64;
    const unsigned short* qpB = qkv + (long)(b * T + qb * 64 + w * 16 + l15) * 3072 + h * 64;
    short8 qfA[2], qfB[2];
    qfA[0] = *reinterpret_cast<const short8*>(qpA + l4 * 8);
    qfA[1] = *reinterpret_cast<const short8*>(qpA + 32 + l4 * 8);
    qfB[0] = *reinterpret_cast<const short8*>(qpB + l4 * 8);
    qfB[1] = *reinterpret_cast<const short8*>(qpB + 32 + l4 * 8);
#pragma unroll
    for (int kk = 0; kk < 2; ++kk)
#pragma unroll
        for (int j = 0; j < 8; ++j) {
            qfA[kk][j] = (short)f2bf(bf2f((unsigned short)qfA[kk][j]) * SC);
            qfB[kk][j] = (short)f2bf(bf2f((unsigned short)qfB[kk][j]) * SC);
        }

    // B-fragment of bf16 ones (for MFMA row-sums)
    short8 onesf;
#pragma unroll
    for (int j = 0; j < 8; ++j) onesf[j] = (short)0x3F80;

    // staging: per-lane pre-swizzled global source (rule #21 both-sides)
    const int lrow  = lane >> 3;               // row within 8-row chunk
    const int lslot = (lane & 7) ^ lrow;       // swizzled 16B source slot
    const unsigned short* kg = qkv + (long)b * T * 3072 + 1024 + h * 64 + lslot * 8;
    const unsigned short* vg = vt + (long)bh * 64 * T + lslot * 8;

    auto stage = [&](int buf, int kt) {
#pragma unroll
        for (int i = 0; i < 2; ++i) {
            const int rb = (w * 2 + i) * 8;    // 8-row chunk base
            gl_lds16(kg + (long)(kt * 64 + rb + lrow) * 3072, &Kb[buf][rb][0]);
            gl_lds16(vg + (long)(rb + lrow) * T + kt * 64,    &Vb[buf][rb][0]);
        }
    };

    f32x4 oA[4] = {}, oB[4] = {};
    f32x4 lsA = {}, lsB = {};          // MFMA-accumulated row sums
    const int qcol = w * 16 + l15;     // this lane's q-row (tile-local)
    const int pswz = (l15 & 7) << 3;   // Ps column XOR swizzle
    int cur = 0;

    // per-tile: S^T = K Q^T -> exp2/mask -> packed P-write -> O += P V, l += P 1
    auto do_tile = [&](const short8 (&qf)[2], f32x4 (&o)[4], f32x4 &ls,
                       bool diag) {
        f32x4 s[4] = {};
        __builtin_amdgcn_s_setprio(1);
#pragma unroll
        for (int kk = 0; kk < 2; ++kk)
#pragma unroll
            for (int c = 0; c < 4; ++c) {
                const int r = c * 16 + l15;
                short8 kf = *reinterpret_cast<const short8*>(
                    &Kb[cur][r][(((kk * 4 + l4) ^ (r & 7)) * 8)]);
                s[c] = __builtin_amdgcn_mfma_f32_16x16x32_bf16(kf, qf[kk], s[c], 0, 0, 0);
            }
        __builtin_amdgcn_s_setprio(0);
        // s[c][i] = S[k_local = c*16+l4*4+i][q_local = l15 (of this wave)]
#pragma unroll
        for (int c = 0; c < 4; ++c) {
            float p0 = exp2f(s[c][0]), p1 = exp2f(s[c][1]);
            float p2 = exp2f(s[c][2]), p3 = exp2f(s[c][3]);
            if (diag) {
                const int kl = c * 16 + l4 * 4;
                if (kl + 0 > qcol) p0 = 0.f;
                if (kl + 1 > qcol) p1 = 0.f;
                if (kl + 2 > qcol) p2 = 0.f;
                if (kl + 3 > qcol) p3 = 0.f;
            }
            unsigned int u01 = (__builtin_bit_cast(unsigned int, p1) & 0xffff0000u) |
                               (__builtin_bit_cast(unsigned int, p0) >> 16);
            unsigned int u23 = (__builtin_bit_cast(unsigned int, p3) & 0xffff0000u) |
                               (__builtin_bit_cast(unsigned int, p2) >> 16);
            const int colb = (c * 16 + l4 * 4) ^ pswz;
            *reinterpret_cast<uint2*>(&Ps[w][l15][colb]) = make_uint2(u01, u23);
        }
        // Ps is wave-private: in-wave ds ordering makes this safe w/o barrier
        __builtin_amdgcn_s_setprio(1);
#pragma unroll
        for (int kk = 0; kk < 2; ++kk) {
            short8 pf = *reinterpret_cast<const short8*>(
                &Ps[w][l15][(kk * 32 + l4 * 8) ^ pswz]);
            ls = __builtin_amdgcn_mfma_f32_16x16x32_bf16(pf, onesf, ls, 0, 0, 0);
#pragma unroll
            for (int nn = 0; nn < 4; ++nn) {
                const int r = nn * 16 + l15;
                short8 vf = *reinterpret_cast<const short8*>(
                    &Vb[cur][r][(((kk * 4 + l4) ^ (r & 7)) * 8)]);
                o[nn] = __builtin_amdgcn_mfma_f32_16x16x32_bf16(pf, vf, o[nn], 0, 0, 0);
            }
        }
        __builtin_amdgcn_s_setprio(0);
    };

    stage(0, 0);
    __syncthreads();                     // builtin vmcnt(0) drain + barrier
    for (int kt = 0; kt <= qb; ++kt) {
        if (kt < qb) stage(cur ^ 1, kt + 1);   // async DMA flies under compute
        do_tile(qfB, oB, lsB, kt == qb);
        if (kt <= qa) do_tile(qfA, oA, lsA, kt == qa);
        __syncthreads();                 // reads done + next tile landed
        cur ^= 1;
    }

    // epilogue: y = O / l (l already per-lane in matching layout, no reduce)
#pragma unroll
    for (int i = 0; i < 4; ++i) {
        float invA = 1.f / lsA[i];
        float invB = 1.f / lsB[i];
        int qArow = qa * 64 + w * 16 + l4 * 4 + i;
        int qBrow = qb * 64 + w * 16 + l4 * 4 + i;
        unsigned short* ypA = y + (long)(b * T + qArow) * 1024 + h * 64;
        unsigned short* ypB = y + (long)(b * T + qBrow) * 1024 + h * 64;
#pragma unroll
        for (int nn = 0; nn < 4; ++nn) {
            ypA[nn * 16 + l15] = f2bf(oA[nn][i] * invA);
            ypB[nn * 16 + l15] = f2bf(oB[nn][i] * invB);
        }
    }
}

extern "C" void kernel_launch(void* const* d_in, const int* in_sizes, int n_in,
                              void* d_out, int out_size, void* d_ws, size_t ws_size,
                              hipStream_t stream) {
    const float* x      = (const float*)d_in[0];
    const float* w_qkv  = (const float*)d_in[1];
    const float* b_qkv  = (const float*)d_in[2];
    const float* w_proj = (const float*)d_in[3];
    const float* b_proj = (const float*)d_in[4];
    float* out = (float*)d_out;

    const int B = 4, T = 2048, C = 1024, H = 16;
    const long M = (long)B * T;  // 8192

    char* ws = (char*)d_ws;
    unsigned short* xb  = (unsigned short*)ws; ws += M * C * 2;            // 16 MB
    unsigned short* wqt = (unsigned short*)ws; ws += (long)3 * C * C * 2;  // 6 MB
    unsigned short* wpt = (unsigned short*)ws; ws += (long)C * C * 2;      // 2 MB
    unsigned short* qkv = (unsigned short*)ws; ws += M * 3 * C * 2;        // 50 MB
    unsigned short* vt  = (unsigned short*)ws; ws += M * C * 2;            // 16 MB
    unsigned short* y   = (unsigned short*)ws; ws += M * C * 2;            // 16 MB

    // 1. fused prep: x convert + both weight transposes (one launch)
    k_prep<<<5120, 256, 0, stream>>>(x, xb, w_qkv, wqt, w_proj, wpt);
    // 2. QKV GEMM (128^2 2-phase + XCD remap, fused V-transpose epilogue)
    {
        dim3 g(M / 128, 3 * C / 128);   // 1536 blocks = 8*192
        k_gemm_bt<0><<<g, 256, 0, stream>>>(xb, wqt, b_qkv, qkv, vt, (int)M, 3 * C, C);
    }
    // 3. causal flash attention -> y bf16 [M][1024]
    {
        dim3 g(T / 128, B * H);
        k_attn<<<g, 256, 0, stream>>>(qkv, vt, y, T);
    }
    // 4. projection GEMM (128^2 2-phase + XCD remap) -> out f32
    {
        dim3 g(M / 128, C / 128);       // 512 blocks = 8*64
        k_gemm_bt<1><<<g, 256, 0, stream>>>(y, wpt, b_proj, out, nullptr, (int)M, C, C);
    }
}

// Round 20
// 171.493 us; speedup vs baseline: 1.1191x; 1.1191x over previous
//
#include <hip/hip_runtime.h>
#include <hip/hip_bf16.h>

typedef __attribute__((ext_vector_type(8))) short short8;
typedef __attribute__((ext_vector_type(4))) float f32x4;

static __device__ __forceinline__ unsigned short f2bf(float f) {
    unsigned int u = __builtin_bit_cast(unsigned int, f);
    u += 0x7fff + ((u >> 16) & 1);   // round-to-nearest-even
    return (unsigned short)(u >> 16);
}

static __device__ __forceinline__ float bf2f(unsigned short u) {
    return __builtin_bit_cast(float, (unsigned int)u << 16);
}

// direct HBM -> LDS DMA, 16B/lane; LDS dest is wave-uniform base (HW adds lane*16)
static __device__ __forceinline__ void gl_lds16(const unsigned short* g, unsigned short* l) {
    __builtin_amdgcn_global_load_lds(
        (const __attribute__((address_space(1))) unsigned int*)g,
        (__attribute__((address_space(3))) unsigned int*)l, 16, 0, 0);
}

// ---------------- fused prep: x->bf16 convert + both weight transposes -----
// 1-D grid, block-range dispatch: [0,4096) convert x (8 f32/thread);
// [4096,4864) transpose w_qkv [1024][3072] -> wqt [3072][1024];
// [4864,5120) transpose w_proj [1024][1024] -> wpt [1024][1024].
__global__ __launch_bounds__(256) void k_prep(
    const float* __restrict__ x,      unsigned short* __restrict__ xb,
    const float* __restrict__ w_qkv,  unsigned short* __restrict__ wqt,
    const float* __restrict__ w_proj, unsigned short* __restrict__ wpt)
{
    __shared__ unsigned short tile[64][72];
    const int id = blockIdx.x;
    const int tid = threadIdx.x;

    if (id < 4096) {                      // x convert: 8.39e6 elems / 8 / 256
        long i = ((long)id * 256 + tid) * 8;
        const f32x4 a = *reinterpret_cast<const f32x4*>(x + i);
        const f32x4 b = *reinterpret_cast<const f32x4*>(x + i + 4);
        union { unsigned short u[8]; uint4 v; } o;
        o.u[0] = f2bf(a[0]); o.u[1] = f2bf(a[1]); o.u[2] = f2bf(a[2]); o.u[3] = f2bf(a[3]);
        o.u[4] = f2bf(b[0]); o.u[5] = f2bf(b[1]); o.u[6] = f2bf(b[2]); o.u[7] = f2bf(b[3]);
        *reinterpret_cast<uint4*>(xb + i) = o.v;
        return;
    }
    const float* w;
    unsigned short* wt;
    int k0, n0, N;
    if (id < 4864) {                      // w_qkv transpose (16 x 48 tiles)
        const int t = id - 4096;
        w = w_qkv; wt = wqt; N = 3072;
        k0 = (t & 15) * 64; n0 = (t >> 4) * 64;
    } else {                              // w_proj transpose (16 x 16 tiles)
        const int t = id - 4864;
        w = w_proj; wt = wpt; N = 1024;
        k0 = (t & 15) * 64; n0 = (t >> 4) * 64;
    }
    const int K = 1024;
#pragma unroll
    for (int it = 0; it < 4; ++it) {
        int idx = it * 256 + tid;          // 1024 float4 chunks
        int kl = idx >> 4;
        int nl = (idx & 15) * 4;
        f32x4 v = *reinterpret_cast<const f32x4*>(w + (long)(k0 + kl) * N + n0 + nl);
        tile[kl][nl + 0] = f2bf(v[0]);
        tile[kl][nl + 1] = f2bf(v[1]);
        tile[kl][nl + 2] = f2bf(v[2]);
        tile[kl][nl + 3] = f2bf(v[3]);
    }
    __syncthreads();
#pragma unroll
    for (int it = 0; it < 2; ++it) {
        int idx = it * 256 + tid;          // 512 chunks of 8
        int nl = idx >> 3;
        int c  = (idx & 7) * 8;
        union { unsigned short u[8]; uint4 v; } o;
#pragma unroll
        for (int j = 0; j < 8; ++j) o.u[j] = tile[c + j][nl];
        *reinterpret_cast<uint4*>(wt + (long)(n0 + nl) * K + k0 + c) = o.v;
    }
}

// ---------------- GEMM: C[M][N] = A[M][K] * Bt[N][K]^T + bias --------------
// A, Bt bf16 K-major; out bf16 (OUTF32=0) or f32 (OUTF32=1).
// 128^2 2-phase dbuf gl_lds + counted vmcnt (R13/R16-R18 verified best).
// NO XCD remap: R19 measured it 8x-inflating HBM A-traffic (FETCH 30->200MB,
// QKV 57->83us) — default round-robin dispatch keeps all XCDs on the same
// A-row band (L3-served reuse); per-XCD chunking expands each L2's working
// set to the full A panel. T1 only helps when per-chunk working sets SHRINK.
// Fused V-transpose epilogue (R17): QKV blocks with n0 >= 2048 write the
// accumulator directly in vt[bh][d][t] layout.
template <int OUTF32>
__global__ __launch_bounds__(256) void k_gemm_bt(
    const unsigned short* __restrict__ A,
    const unsigned short* __restrict__ Bt,
    const float* __restrict__ bias,
    void* __restrict__ Cv,
    unsigned short* __restrict__ vtout,   // nullptr for proj
    int M, int N, int K)
{
    __shared__ __align__(16) unsigned short As[2][128][64];
    __shared__ __align__(16) unsigned short Bs[2][128][64];
    const int tid = threadIdx.x;
    const int m0 = blockIdx.x * 128;
    const int n0 = blockIdx.y * 128;
    const int w = tid >> 6, lane = tid & 63;
    const int wr = (w >> 1) * 64, wc = (w & 1) * 64;
    const int l4 = lane >> 4, l15 = lane & 15;
    // staging: per-lane pre-swizzled global source slot
    const int lrow  = lane >> 3;               // row within 8-row chunk
    const int lslot = (lane & 7) ^ lrow;       // swizzled 16B source slot

    auto stage = [&](int buf, int k0) {        // 8 gl_lds per wave
#pragma unroll
        for (int it = 0; it < 4; ++it) {
            const int rb = (w * 4 + it) * 8;   // 8-row chunk base
            gl_lds16(A  + (long)(m0 + rb + lrow) * K + k0 + lslot * 8, &As[buf][rb][0]);
            gl_lds16(Bt + (long)(n0 + rb + lrow) * K + k0 + lslot * 8, &Bs[buf][rb][0]);
        }
    };

    f32x4 acc[4][4] = {};
    const int nk = K / 64;
    stage(0, 0);
    for (int kt = 0; kt < nk; ++kt) {
        const int cur = kt & 1;
        if (kt + 1 < nk) {
            stage(cur ^ 1, (kt + 1) * 64);     // 8 loads stay in flight
            asm volatile("s_waitcnt vmcnt(8)" ::: "memory");   // stage-kt landed
        } else {
            asm volatile("s_waitcnt vmcnt(0)" ::: "memory");
        }
        __builtin_amdgcn_sched_barrier(0);
        __builtin_amdgcn_s_barrier();          // all waves' stage-kt landed
        __builtin_amdgcn_sched_barrier(0);
#pragma unroll
        for (int kk = 0; kk < 2; ++kk) {
            short8 af[4], bf[4];
#pragma unroll
            for (int m = 0; m < 4; ++m) {
                const int r = wr + m * 16 + l15;
                af[m] = *reinterpret_cast<const short8*>(&As[cur][r][((kk * 4 + l4) ^ (r & 7)) * 8]);
            }
#pragma unroll
            for (int n = 0; n < 4; ++n) {
                const int r = wc + n * 16 + l15;
                bf[n] = *reinterpret_cast<const short8*>(&Bs[cur][r][((kk * 4 + l4) ^ (r & 7)) * 8]);
            }
#pragma unroll
            for (int m = 0; m < 4; ++m)
#pragma unroll
                for (int n = 0; n < 4; ++n)
                    acc[m][n] = __builtin_amdgcn_mfma_f32_16x16x32_bf16(af[m], bf[n], acc[m][n], 0, 0, 0);
        }
        __builtin_amdgcn_sched_barrier(0);
        asm volatile("s_waitcnt lgkmcnt(0)" ::: "memory");   // my LDS reads done
        __builtin_amdgcn_s_barrier();          // everyone's reads done -> buffer reusable
        __builtin_amdgcn_sched_barrier(0);
    }
    // epilogue
    if (!OUTF32 && vtout && n0 >= 2048) {
        // V-third of QKV: write directly in vt[bh=b*16+hd][d][t] layout.
#pragma unroll
        for (int n = 0; n < 4; ++n) {
            const int col = n0 + wc + n * 16 + l15;       // 2048..3071
            const float bv = bias[col];
            const int cp = col - 2048;                    // 0..1023
            const int hd = cp >> 6, d = cp & 63;
#pragma unroll
            for (int m = 0; m < 4; ++m) {
                const int row0 = m0 + wr + m * 16 + l4 * 4;   // 4 consecutive t
                const int b = row0 >> 11;                 // /2048
                const int t = row0 & 2047;
                unsigned int u01 =
                    ((unsigned int)f2bf(acc[m][n][1] + bv) << 16) |
                    (unsigned int)f2bf(acc[m][n][0] + bv);
                unsigned int u23 =
                    ((unsigned int)f2bf(acc[m][n][3] + bv) << 16) |
                    (unsigned int)f2bf(acc[m][n][2] + bv);
                *reinterpret_cast<uint2*>(
                    vtout + ((long)(b * 16 + hd) * 64 + d) * 2048 + t) =
                    make_uint2(u01, u23);
            }
        }
        return;
    }
#pragma unroll
    for (int n = 0; n < 4; ++n) {
        const int col = n0 + wc + n * 16 + l15;
        const float bv = bias[col];
#pragma unroll
        for (int m = 0; m < 4; ++m) {
            const int row = m0 + wr + m * 16 + l4 * 4;
#pragma unroll
            for (int i = 0; i < 4; ++i) {
                float v = acc[m][n][i] + bv;
                if (OUTF32)
                    reinterpret_cast<float*>(Cv)[(long)(row + i) * N + col] = v;
                else
                    reinterpret_cast<unsigned short*>(Cv)[(long)(row + i) * N + col] = f2bf(v);
            }
        }
    }
}

// ---------------- causal flash attention v6 (R12/R16-R18 known-good) -------
// Paired q-tiles sequential, gl_lds dbuf + both-sides swizzle, XCD remap,
// fixed-max softmax, MFMA row-sums, setprio, swapped QK^T + packed P-writes.
__global__ __launch_bounds__(256, 4) void k_attn(
    const unsigned short* __restrict__ qkv,
    const unsigned short* __restrict__ vt,
    unsigned short* __restrict__ y, int T)
{
    __shared__ __align__(16) unsigned short Kb[2][64][64];
    __shared__ __align__(16) unsigned short Vb[2][64][64];
    __shared__ __align__(16) unsigned short Ps[4][16][64];   // [wave][q][k]
    const int nQT = T >> 6;

    // XCD-aware bijective remap (1024 = 8 * 128, exact)
    int n = blockIdx.x + gridDim.x * blockIdx.y;          // 0..1023
    n = (n & 7) * ((gridDim.x * gridDim.y) >> 3) + (n >> 3);
    const int qa = n & 15;                // 0..15
    const int qb = nQT - 1 - qa;          // 31..16
    const int bh = n >> 4;
    const int b = bh >> 4, h = bh & 15;
    const int tid = threadIdx.x, w = tid >> 6, lane = tid & 63;
    const int l4 = lane >> 4, l15 = lane & 15;

    const float SC = 0.125f * 1.44269504f;  // 1/sqrt(64) * log2(e)

    // Q fragments for both tiles, pre-scaled by SC
    const unsigned short* qpA = qkv + (long)(b * T + qa * 64 + w * 16 + l15) * 3072 + h * 64;
    const unsigned short* qpB = qkv + (long)(b * T + qb * 64 + w * 16 + l15) * 3072 + h * 64;
    short8 qfA[2], qfB[2];
    qfA[0] = *reinterpret_cast<const short8*>(qpA + l4 * 8);
    qfA[1] = *reinterpret_cast<const short8*>(qpA + 32 + l4 * 8);
    qfB[0] = *reinterpret_cast<const short8*>(qpB + l4 * 8);
    qfB[1] = *reinterpret_cast<const short8*>(qpB + 32 + l4 * 8);
#pragma unroll
    for (int kk = 0; kk < 2; ++kk)
#pragma unroll
        for (int j = 0; j < 8; ++j) {
            qfA[kk][j] = (short)f2bf(bf2f((unsigned short)qfA[kk][j]) * SC);
            qfB[kk][j] = (short)f2bf(bf2f((unsigned short)qfB[kk][j]) * SC);
        }

    // B-fragment of bf16 ones (for MFMA row-sums)
    short8 onesf;
#pragma unroll
    for (int j = 0; j < 8; ++j) onesf[j] = (short)0x3F80;

    // staging: per-lane pre-swizzled global source (rule #21 both-sides)
    const int lrow  = lane >> 3;               // row within 8-row chunk
    const int lslot = (lane & 7) ^ lrow;       // swizzled 16B source slot
    const unsigned short* kg = qkv + (long)b * T * 3072 + 1024 + h * 64 + lslot * 8;
    const unsigned short* vg = vt + (long)bh * 64 * T + lslot * 8;

    auto stage = [&](int buf, int kt) {
#pragma unroll
        for (int i = 0; i < 2; ++i) {
            const int rb = (w * 2 + i) * 8;    // 8-row chunk base
            gl_lds16(kg + (long)(kt * 64 + rb + lrow) * 3072, &Kb[buf][rb][0]);
            gl_lds16(vg + (long)(rb + lrow) * T + kt * 64,    &Vb[buf][rb][0]);
        }
    };

    f32x4 oA[4] = {}, oB[4] = {};
    f32x4 lsA = {}, lsB = {};          // MFMA-accumulated row sums
    const int qcol = w * 16 + l15;     // this lane's q-row (tile-local)
    const int pswz = (l15 & 7) << 3;   // Ps column XOR swizzle
    int cur = 0;

    // per-tile: S^T = K Q^T -> exp2/mask -> packed P-write -> O += P V, l += P 1
    auto do_tile = [&](const short8 (&qf)[2], f32x4 (&o)[4], f32x4 &ls,
                       bool diag) {
        f32x4 s[4] = {};
        __builtin_amdgcn_s_setprio(1);
#pragma unroll
        for (int kk = 0; kk < 2; ++kk)
#pragma unroll
            for (int c = 0; c < 4; ++c) {
                const int r = c * 16 + l15;
                short8 kf = *reinterpret_cast<const short8*>(
                    &Kb[cur][r][(((kk * 4 + l4) ^ (r & 7)) * 8)]);
                s[c] = __builtin_amdgcn_mfma_f32_16x16x32_bf16(kf, qf[kk], s[c], 0, 0, 0);
            }
        __builtin_amdgcn_s_setprio(0);
        // s[c][i] = S[k_local = c*16+l4*4+i][q_local = l15 (of this wave)]
#pragma unroll
        for (int c = 0; c < 4; ++c) {
            float p0 = exp2f(s[c][0]), p1 = exp2f(s[c][1]);
            float p2 = exp2f(s[c][2]), p3 = exp2f(s[c][3]);
            if (diag) {
                const int kl = c * 16 + l4 * 4;
                if (kl + 0 > qcol) p0 = 0.f;
                if (kl + 1 > qcol) p1 = 0.f;
                if (kl + 2 > qcol) p2 = 0.f;
                if (kl + 3 > qcol) p3 = 0.f;
            }
            unsigned int u01 = (__builtin_bit_cast(unsigned int, p1) & 0xffff0000u) |
                               (__builtin_bit_cast(unsigned int, p0) >> 16);
            unsigned int u23 = (__builtin_bit_cast(unsigned int, p3) & 0xffff0000u) |
                               (__builtin_bit_cast(unsigned int, p2) >> 16);
            const int colb = (c * 16 + l4 * 4) ^ pswz;
            *reinterpret_cast<uint2*>(&Ps[w][l15][colb]) = make_uint2(u01, u23);
        }
        // Ps is wave-private: in-wave ds ordering makes this safe w/o barrier
        __builtin_amdgcn_s_setprio(1);
#pragma unroll
        for (int kk = 0; kk < 2; ++kk) {
            short8 pf = *reinterpret_cast<const short8*>(
                &Ps[w][l15][(kk * 32 + l4 * 8) ^ pswz]);
            ls = __builtin_amdgcn_mfma_f32_16x16x32_bf16(pf, onesf, ls, 0, 0, 0);
#pragma unroll
            for (int nn = 0; nn < 4; ++nn) {
                const int r = nn * 16 + l15;
                short8 vf = *reinterpret_cast<const short8*>(
                    &Vb[cur][r][(((kk * 4 + l4) ^ (r & 7)) * 8)]);
                o[nn] = __builtin_amdgcn_mfma_f32_16x16x32_bf16(pf, vf, o[nn], 0, 0, 0);
            }
        }
        __builtin_amdgcn_s_setprio(0);
    };

    stage(0, 0);
    __syncthreads();                     // builtin vmcnt(0) drain + barrier
    for (int kt = 0; kt <= qb; ++kt) {
        if (kt < qb) stage(cur ^ 1, kt + 1);   // async DMA flies under compute
        do_tile(qfB, oB, lsB, kt == qb);
        if (kt <= qa) do_tile(qfA, oA, lsA, kt == qa);
        __syncthreads();                 // reads done + next tile landed
        cur ^= 1;
    }

    // epilogue: y = O / l (l already per-lane in matching layout, no reduce)
#pragma unroll
    for (int i = 0; i < 4; ++i) {
        float invA = 1.f / lsA[i];
        float invB = 1.f / lsB[i];
        int qArow = qa * 64 + w * 16 + l4 * 4 + i;
        int qBrow = qb * 64 + w * 16 + l4 * 4 + i;
        unsigned short* ypA = y + (long)(b * T + qArow) * 1024 + h * 64;
        unsigned short* ypB = y + (long)(b * T + qBrow) * 1024 + h * 64;
#pragma unroll
        for (int nn = 0; nn < 4; ++nn) {
            ypA[nn * 16 + l15] = f2bf(oA[nn][i] * invA);
            ypB[nn * 16 + l15] = f2bf(oB[nn][i] * invB);
        }
    }
}

extern "C" void kernel_launch(void* const* d_in, const int* in_sizes, int n_in,
                              void* d_out, int out_size, void* d_ws, size_t ws_size,
                              hipStream_t stream) {
    const float* x      = (const float*)d_in[0];
    const float* w_qkv  = (const float*)d_in[1];
    const float* b_qkv  = (const float*)d_in[2];
    const float* w_proj = (const float*)d_in[3];
    const float* b_proj = (const float*)d_in[4];
    float* out = (float*)d_out;

    const int B = 4, T = 2048, C = 1024, H = 16;
    const long M = (long)B * T;  // 8192

    char* ws = (char*)d_ws;
    unsigned short* xb  = (unsigned short*)ws; ws += M * C * 2;            // 16 MB
    unsigned short* wqt = (unsigned short*)ws; ws += (long)3 * C * C * 2;  // 6 MB
    unsigned short* wpt = (unsigned short*)ws; ws += (long)C * C * 2;      // 2 MB
    unsigned short* qkv = (unsigned short*)ws; ws += M * 3 * C * 2;        // 50 MB
    unsigned short* vt  = (unsigned short*)ws; ws += M * C * 2;            // 16 MB
    unsigned short* y   = (unsigned short*)ws; ws += M * C * 2;            // 16 MB

    // 1. fused prep: x convert + both weight transposes (one launch)
    k_prep<<<5120, 256, 0, stream>>>(x, xb, w_qkv, wqt, w_proj, wpt);
    // 2. QKV GEMM (128^2 2-phase, fused V-transpose epilogue) -> qkv + vt
    {
        dim3 g(M / 128, 3 * C / 128);
        k_gemm_bt<0><<<g, 256, 0, stream>>>(xb, wqt, b_qkv, qkv, vt, (int)M, 3 * C, C);
    }
    // 3. causal flash attention -> y bf16 [M][1024]
    {
        dim3 g(T / 128, B * H);
        k_attn<<<g, 256, 0, stream>>>(qkv, vt, y, T);
    }
    // 4. projection GEMM (128^2 2-phase, no vt) -> out f32
    {
        dim3 g(M / 128, C / 128);
        k_gemm_bt<1><<<g, 256, 0, stream>>>(y, wpt, b_proj, out, nullptr, (int)M, C, C);
    }
}